// Round 1
// baseline (162.740 us; speedup 1.0000x reference)
//
#include <hip/hip_runtime.h>
#include <math.h>

// Problem constants (fixed by reference setup_inputs)
constexpr int CIN  = 256;
constexpr int NST  = 512;          // N
constexpr int LSEQ = 4096;
constexpr int BB   = 4;
constexpr int ROWS = BB * LSEQ;    // 16384
constexpr int COUT = 256;
constexpr int LC   = 32;           // scan chunk length (2 chunks per 64-row proj tile)
constexpr int NC   = LSEQ / LC;    // 128 chunks per batch

typedef __attribute__((ext_vector_type(8))) short bf16x8;
typedef __attribute__((ext_vector_type(4))) float f32x4;
typedef unsigned short ushort_t;
typedef unsigned int   uint_t;

__device__ __forceinline__ ushort_t f2bf(float f) {
    uint_t u = __float_as_uint(f);
    u = (u + 0x7FFF + ((u >> 16) & 1)) >> 16;   // RNE
    return (ushort_t)u;
}
__device__ __forceinline__ float bf2f(ushort_t s) {
    return __uint_as_float(((uint_t)s) << 16);
}

// ---------------------------------------------------------------------------
// prep: fused weight conversion (bf16, transposed [n][k]) + x conversion.
// Block-granular branch: blocks [0, WBLOCKS) do weights, rest do x.
// ---------------------------------------------------------------------------
constexpr int WELEMS  = 4 * NST * CIN + COUT * NST;   // 655360
constexpr int WBLOCKS = WELEMS / 256;                 // 2560
constexpr int XBLOCKS = (ROWS * CIN / 4) / 256;       // 4096

__global__ __launch_bounds__(256)
void prep_kernel(const float* __restrict__ Wx, const float* __restrict__ Wbc,
                 const float* __restrict__ Wd, const float* __restrict__ Wy,
                 const float* __restrict__ x,
                 ushort_t* __restrict__ Wt, ushort_t* __restrict__ Wyt,
                 ushort_t* __restrict__ xb)
{
    const int bid = blockIdx.x;
    if (bid < WBLOCKS) {
        const int gid = bid * 256 + threadIdx.x;
        if (gid < 4 * NST * CIN) {
            const int mat = gid >> 17;            // 512*256 = 131072 per mat
            const int idx = gid & 131071;
            const int k   = idx >> 9;             // 0..255
            const int n   = idx & 511;            // 0..511 (coalesced reads)
            float v;
            if      (mat == 0) v = Wx [k * NST + n];
            else if (mat == 1) v = Wbc[k * (2 * NST) + n];
            else if (mat == 2) v = Wbc[k * (2 * NST) + NST + n];
            else               v = Wd [k * NST + n];
            Wt[((size_t)mat * NST + n) * CIN + k] = f2bf(v);
        } else {
            const int idx = gid - 4 * NST * CIN;  // 0 .. 512*256-1
            const int k   = idx >> 8;             // 0..511
            const int n   = idx & 255;            // 0..255
            Wyt[(size_t)n * NST + k] = f2bf(Wy[k * COUT + n]);
        }
    } else {
        const int i = ((bid - WBLOCKS) * 256 + threadIdx.x) * 4;
        float4 v = *(const float4*)&x[i];
        uint2 o;
        o.x = (uint_t)f2bf(v.x) | ((uint_t)f2bf(v.y) << 16);
        o.y = (uint_t)f2bf(v.z) | ((uint_t)f2bf(v.w) << 16);
        *(uint2*)&xb[i] = o;
    }
}

// ---------------------------------------------------------------------------
// proj_mfma: fused 4-matrix projection GEMM (16x16x32 bf16 MFMA) + epilogue
// + IN-BLOCK chunk-local scan (replaces the old scan_local kernel).
// Tile: 64 rows x 64 n x 4 mats. The 64-row tile == 2 scan chunks of LC=32.
// After the epilogue, (A,u) for the full 64x64 (t x n) tile is re-staged into
// an LDS overlay of the dead GEMM staging buffers; 4 segments of 16 t are
// scanned in parallel and pairwise-combined into per-chunk (Aprod, Hend).
// A/u are also written interleaved as float2 for vectorized scan_final loads.
// ---------------------------------------------------------------------------
__global__ __launch_bounds__(256, 3)
void proj_mfma_kernel(const ushort_t* __restrict__ xb, const ushort_t* __restrict__ Wt,
                      const float* __restrict__ bx, const float* __restrict__ bbc,
                      const float* __restrict__ bd,
                      float2* __restrict__ AU, ushort_t* __restrict__ CYb,
                      float* __restrict__ Aprod, float* __restrict__ Hend)
{
    // GEMM phase: xs 64x72 bf16 (9216 B) + ws 4x64x72 bf16 (36864 B) = 46080 B
    // scan phase overlay: aus [64][65] float2 (33280 B) + comb [4][64] float2 (2048 B)
    __shared__ alignas(16) char smem[46080];
    ushort_t (*xs)[72]     = (ushort_t(*)[72])smem;
    ushort_t (*ws)[64][72] = (ushort_t(*)[64][72])(smem + 9216);
    float2   (*aus)[65]    = (float2(*)[65])smem;
    float2   (*comb)[64]   = (float2(*)[64])(smem + 33280);

    const int tid  = threadIdx.x;
    const int wave = tid >> 6;
    const int lane = tid & 63;
    const int lm   = lane & 15;       // 16-dim index (row for A, n for B/D)
    const int lq   = lane >> 4;       // k-quad / row-quad
    const int row0 = blockIdx.x * 64;
    const int n0   = blockIdx.y * 64;

    // staging assignment: thread t -> row/n = t>>2, k-quad16 = (t&3)*16
    const int sr = tid >> 2;
    const int sk = (tid & 3) << 4;

    f32x4 acc[4][4];                  // [rowtile][mat]
    #pragma unroll
    for (int rt = 0; rt < 4; ++rt)
        #pragma unroll
        for (int m = 0; m < 4; ++m)
            acc[rt][m] = (f32x4){0.f, 0.f, 0.f, 0.f};

    const ushort_t* xsrc  = xb + (size_t)(row0 + sr) * CIN + sk;
    const ushort_t* wsrc0 = Wt + (size_t)(n0 + sr) * CIN + sk;   // mat stride = NST*CIN

    for (int k0 = 0; k0 < CIN; k0 += 64) {
        uint4 xv0 = *(const uint4*)(xsrc + k0);
        uint4 xv1 = *(const uint4*)(xsrc + k0 + 8);
        uint4 wv[4][2];
        #pragma unroll
        for (int m = 0; m < 4; ++m) {
            const ushort_t* p = wsrc0 + (size_t)m * NST * CIN + k0;
            wv[m][0] = *(const uint4*)(p);
            wv[m][1] = *(const uint4*)(p + 8);
        }
        *(uint4*)&xs[sr][sk]     = xv0;
        *(uint4*)&xs[sr][sk + 8] = xv1;
        #pragma unroll
        for (int m = 0; m < 4; ++m) {
            *(uint4*)&ws[m][sr][sk]     = wv[m][0];
            *(uint4*)&ws[m][sr][sk + 8] = wv[m][1];
        }
        __syncthreads();

        #pragma unroll
        for (int ks = 0; ks < 2; ++ks) {
            const int kk = ks * 32 + lq * 8;
            bf16x8 af[4], bf[4];
            #pragma unroll
            for (int rt = 0; rt < 4; ++rt)
                af[rt] = *(const bf16x8*)&xs[rt * 16 + lm][kk];
            #pragma unroll
            for (int m = 0; m < 4; ++m)
                bf[m] = *(const bf16x8*)&ws[m][wave * 16 + lm][kk];
            #pragma unroll
            for (int rt = 0; rt < 4; ++rt)
                #pragma unroll
                for (int m = 0; m < 4; ++m)
                    acc[rt][m] = __builtin_amdgcn_mfma_f32_16x16x32_bf16(
                        af[rt], bf[m], acc[rt][m], 0, 0, 0);
        }
        __syncthreads();   // also fences last GEMM-phase LDS reads before overlay
    }

    // epilogue: in-lane, n fixed per lane
    const int nl = wave * 16 + lm;    // local n within tile
    const int ng = n0 + nl;
    const float bxv = bx [ng];
    const float bbv = bbc[ng];
    const float bcv = bbc[NST + ng];
    const float bdv = bd [ng];
    #pragma unroll
    for (int rt = 0; rt < 4; ++rt) {
        #pragma unroll
        for (int r = 0; r < 4; ++r) {
            const int t   = rt * 16 + lq * 4 + r;    // 0..63 within tile
            const int row = row0 + t;
            float xp = acc[rt][0][r] + bxv;
            float bm = acc[rt][1][r] + bbv;
            float cc = acc[rt][2][r] + bcv;
            float dd = acc[rt][3][r] + bdv;
            dd = fminf(dd, 60.0f);
            float e  = __expf(dd);
            float A  = 1.0f / (1.0f + e);        // exp(-softplus(d))
            float u  = (e * A) * bm * xp;        // (1-A)*Bm*x_proj
            const size_t idx = (size_t)row * NST + ng;
            AU[idx]  = make_float2(A, u);
            CYb[idx] = f2bf(cc);
            aus[t][nl] = make_float2(A, u);
        }
    }
    __syncthreads();

    // chunk-local scan: 4 segments x 16 t each, one n-column per thread
    {
        const int n  = tid & 63;
        const int sg = tid >> 6;                 // 0..3
        float ap = 1.0f, h = 0.0f;
        #pragma unroll
        for (int i = 0; i < 16; ++i) {
            float2 au = aus[sg * 16 + i][n];
            ap *= au.x;
            h  = fmaf(au.x, h, au.y);
        }
        comb[sg][n] = make_float2(ap, h);
    }
    __syncthreads();

    // combine segment pairs -> per-chunk (Aprod, Hend); tile = chunks 2*bx, 2*bx+1
    if (tid < 128) {
        const int n  = tid & 63;
        const int ch = tid >> 6;                 // 0..1
        float2 c0 = comb[ch * 2 + 0][n];
        float2 c1 = comb[ch * 2 + 1][n];
        const size_t ci = (size_t)(blockIdx.x * 2 + ch) * NST + (n0 + n);
        Aprod[ci] = c0.x * c1.x;
        Hend[ci]  = fmaf(c1.x, c0.y, c1.y);
    }
}

// ---------------------------------------------------------------------------
// scan_carry: serial carry across NC=128 chunks per (b, n). Tiny (2048 cols).
// ---------------------------------------------------------------------------
__global__ __launch_bounds__(256)
void scan_carry_kernel(const float* __restrict__ Aprod, const float* __restrict__ Hend,
                       float* __restrict__ Carry)
{
    const int gid = blockIdx.x * 256 + threadIdx.x;   // 0 .. BB*NST-1
    const int n   = gid & (NST - 1);
    const int b   = gid >> 9;
    float h = 0.0f;
    for (int c = 0; c < NC; ++c) {
        size_t idx = ((size_t)(b * NC + c)) * NST + n;
        Carry[idx] = h;
        h = fmaf(Aprod[idx], h, Hend[idx]);
    }
}

// ---------------------------------------------------------------------------
// scan_final: apply carries, produce y = C*h in-place (bf16 CYb).
// float2 AU loads (8 B/lane); 1024 blocks = 16 waves/CU.
// ---------------------------------------------------------------------------
__global__ __launch_bounds__(256)
void scan_final_kernel(const float2* __restrict__ AU, ushort_t* __restrict__ CYb,
                       const float* __restrict__ Carry)
{
    const int gid = blockIdx.x * 256 + threadIdx.x;   // 0 .. BB*NC*NST-1
    const int n   = gid & (NST - 1);
    const int bc  = gid >> 9;                         // global chunk 0..511
    const size_t base = (size_t)bc * LC * NST + n;
    float h = Carry[(size_t)bc * NST + n];
    #pragma unroll 8
    for (int t = 0; t < LC; ++t) {
        size_t idx = base + (size_t)t * NST;
        float2 au = AU[idx];
        float cc  = bf2f(CYb[idx]);
        h = fmaf(au.x, h, au.y);
        CYb[idx] = f2bf(cc * h);     // y overwrites C (same slot, same thread)
    }
}

// ---------------------------------------------------------------------------
// out_mfma: out = y @ Wy + by via 16x16x32 bf16 MFMA. Tile 64 rows x 64 cols.
// ---------------------------------------------------------------------------
__global__ __launch_bounds__(256, 4)
void out_mfma_kernel(const ushort_t* __restrict__ yb, const ushort_t* __restrict__ Wyt,
                     const float* __restrict__ by, float* __restrict__ out)
{
    __shared__ alignas(16) ushort_t ys [64][72];
    __shared__ alignas(16) ushort_t wys[64][72];

    const int tid  = threadIdx.x;
    const int wave = tid >> 6;
    const int lane = tid & 63;
    const int lm   = lane & 15;
    const int lq   = lane >> 4;
    const int row0 = blockIdx.x * 64;
    const int n0   = blockIdx.y * 64;

    const int sr = tid >> 2;
    const int sk = (tid & 3) << 4;

    f32x4 acc[4];
    #pragma unroll
    for (int rt = 0; rt < 4; ++rt) acc[rt] = (f32x4){0.f, 0.f, 0.f, 0.f};

    const ushort_t* ysrc = yb  + (size_t)(row0 + sr) * NST + sk;
    const ushort_t* wsrc = Wyt + (size_t)(n0  + sr) * NST + sk;

    for (int k0 = 0; k0 < NST; k0 += 64) {
        uint4 yv0 = *(const uint4*)(ysrc + k0);
        uint4 yv1 = *(const uint4*)(ysrc + k0 + 8);
        uint4 wv0 = *(const uint4*)(wsrc + k0);
        uint4 wv1 = *(const uint4*)(wsrc + k0 + 8);
        *(uint4*)&ys [sr][sk]     = yv0;
        *(uint4*)&ys [sr][sk + 8] = yv1;
        *(uint4*)&wys[sr][sk]     = wv0;
        *(uint4*)&wys[sr][sk + 8] = wv1;
        __syncthreads();

        #pragma unroll
        for (int ks = 0; ks < 2; ++ks) {
            const int kk = ks * 32 + lq * 8;
            bf16x8 bfr = *(const bf16x8*)&wys[wave * 16 + lm][kk];
            #pragma unroll
            for (int rt = 0; rt < 4; ++rt) {
                bf16x8 af = *(const bf16x8*)&ys[rt * 16 + lm][kk];
                acc[rt] = __builtin_amdgcn_mfma_f32_16x16x32_bf16(
                    af, bfr, acc[rt], 0, 0, 0);
            }
        }
        __syncthreads();
    }

    const int ng = n0 + wave * 16 + lm;
    const float bv = by[ng];
    #pragma unroll
    for (int rt = 0; rt < 4; ++rt)
        #pragma unroll
        for (int r = 0; r < 4; ++r) {
            const int row = row0 + rt * 16 + lq * 4 + r;
            out[(size_t)row * COUT + ng] = acc[rt][r] + bv;
        }
}

// ---------------------------------------------------------------------------
// Workspace layout (bytes, all 16B aligned):
//   AU    float2 ROWS*NST    67,108,864  (A,u interleaved)
//   CYb   bf16   ROWS*NST    16,777,216  (C from proj; y in-place after scan)
//   xb    bf16   ROWS*CIN     8,388,608
//   Wt    bf16   4*NST*CIN    1,048,576
//   Wyt   bf16   COUT*NST       262,144
//   Aprod fp32   BB*NC*NST    1,048,576
//   Hend  fp32   BB*NC*NST    1,048,576
//   Carry fp32   BB*NC*NST    1,048,576
// total 96,731,136 B (< 102.2 MB proven available previously)
// ---------------------------------------------------------------------------
extern "C" void kernel_launch(void* const* d_in, const int* in_sizes, int n_in,
                              void* d_out, int out_size, void* d_ws, size_t ws_size,
                              hipStream_t stream)
{
    const float* x   = (const float*)d_in[0];
    const float* Wx  = (const float*)d_in[1];
    const float* bx  = (const float*)d_in[2];
    const float* Wbc = (const float*)d_in[3];
    const float* bbc = (const float*)d_in[4];
    const float* Wd  = (const float*)d_in[5];
    const float* bd  = (const float*)d_in[6];
    const float* Wy  = (const float*)d_in[7];
    const float* by  = (const float*)d_in[8];
    float* out = (float*)d_out;

    char* p = (char*)d_ws;
    float2*   AU    = (float2*)p;         p += (size_t)ROWS * NST * 8;
    ushort_t* CYb   = (ushort_t*)p;       p += (size_t)ROWS * NST * 2;
    ushort_t* xb    = (ushort_t*)p;       p += (size_t)ROWS * CIN * 2;
    ushort_t* Wt    = (ushort_t*)p;       p += (size_t)4 * NST * CIN * 2;
    ushort_t* Wyt   = (ushort_t*)p;       p += (size_t)COUT * NST * 2;
    float*    Aprod = (float*)p;          p += (size_t)BB * NC * NST * 4;
    float*    Hend  = (float*)p;          p += (size_t)BB * NC * NST * 4;
    float*    Carry = (float*)p;          p += (size_t)BB * NC * NST * 4;

    prep_kernel<<<WBLOCKS + XBLOCKS, 256, 0, stream>>>(
        Wx, Wbc, Wd, Wy, x, Wt, Wyt, xb);

    proj_mfma_kernel<<<dim3(ROWS / 64, NST / 64), 256, 0, stream>>>(
        xb, Wt, bx, bbc, bd, AU, CYb, Aprod, Hend);

    scan_carry_kernel<<<(BB * NST) / 256, 256, 0, stream>>>(
        Aprod, Hend, Carry);

    scan_final_kernel<<<(BB * NC * NST) / 256, 256, 0, stream>>>(
        AU, CYb, Carry);

    out_mfma_kernel<<<dim3(ROWS / 64, COUT / 64), 256, 0, stream>>>(
        CYb, Wyt, by, out);
}

// Round 2
// 147.763 us; speedup vs baseline: 1.1014x; 1.1014x over previous
//
#include <hip/hip_runtime.h>
#include <hip/hip_fp16.h>
#include <math.h>

// Problem constants (fixed by reference setup_inputs)
constexpr int CIN  = 256;
constexpr int NST  = 512;          // N
constexpr int LSEQ = 4096;
constexpr int BB   = 4;
constexpr int ROWS = BB * LSEQ;    // 16384
constexpr int COUT = 256;
constexpr int LC   = 32;           // scan chunk length (2 chunks per 64-row proj tile)
constexpr int NC   = LSEQ / LC;    // 128 chunks per batch

typedef __attribute__((ext_vector_type(8))) short bf16x8;
typedef __attribute__((ext_vector_type(4))) float f32x4;
typedef unsigned short ushort_t;
typedef unsigned int   uint_t;

__device__ __forceinline__ ushort_t f2bf(float f) {
    uint_t u = __float_as_uint(f);
    u = (u + 0x7FFF + ((u >> 16) & 1)) >> 16;   // RNE
    return (ushort_t)u;
}
__device__ __forceinline__ float bf2f(ushort_t s) {
    return __uint_as_float(((uint_t)s) << 16);
}

// ---------------------------------------------------------------------------
// prep: fused weight conversion (bf16, transposed [n][k]) + x conversion.
// ---------------------------------------------------------------------------
constexpr int WELEMS  = 4 * NST * CIN + COUT * NST;   // 655360
constexpr int WBLOCKS = WELEMS / 256;                 // 2560
constexpr int XBLOCKS = (ROWS * CIN / 4) / 256;       // 4096

__global__ __launch_bounds__(256)
void prep_kernel(const float* __restrict__ Wx, const float* __restrict__ Wbc,
                 const float* __restrict__ Wd, const float* __restrict__ Wy,
                 const float* __restrict__ x,
                 ushort_t* __restrict__ Wt, ushort_t* __restrict__ Wyt,
                 ushort_t* __restrict__ xb)
{
    const int bid = blockIdx.x;
    if (bid < WBLOCKS) {
        const int gid = bid * 256 + threadIdx.x;
        if (gid < 4 * NST * CIN) {
            const int mat = gid >> 17;            // 512*256 = 131072 per mat
            const int idx = gid & 131071;
            const int k   = idx >> 9;             // 0..255
            const int n   = idx & 511;            // 0..511 (coalesced reads)
            float v;
            if      (mat == 0) v = Wx [k * NST + n];
            else if (mat == 1) v = Wbc[k * (2 * NST) + n];
            else if (mat == 2) v = Wbc[k * (2 * NST) + NST + n];
            else               v = Wd [k * NST + n];
            Wt[((size_t)mat * NST + n) * CIN + k] = f2bf(v);
        } else {
            const int idx = gid - 4 * NST * CIN;  // 0 .. 512*256-1
            const int k   = idx >> 8;             // 0..511
            const int n   = idx & 255;            // 0..255
            Wyt[(size_t)n * NST + k] = f2bf(Wy[k * COUT + n]);
        }
    } else {
        const int i = ((bid - WBLOCKS) * 256 + threadIdx.x) * 4;
        float4 v = *(const float4*)&x[i];
        uint2 o;
        o.x = (uint_t)f2bf(v.x) | ((uint_t)f2bf(v.y) << 16);
        o.y = (uint_t)f2bf(v.z) | ((uint_t)f2bf(v.w) << 16);
        *(uint2*)&xb[i] = o;
    }
}

// ---------------------------------------------------------------------------
// proj_mfma: fused 4-matrix projection GEMM (16x16x32 bf16 MFMA) + epilogue
// + in-block chunk-local scan.
//  - AU written as packed fp16 (A,u) pairs (4 B) — halves the dominant write.
//  - C staged through LDS, written as 128 B-contiguous rows (no partial-line RMW).
//  - chunk summaries written as interleaved float2 AHc[chunk][n].
// ---------------------------------------------------------------------------
__global__ __launch_bounds__(256, 3)
void proj_mfma_kernel(const ushort_t* __restrict__ xb, const ushort_t* __restrict__ Wt,
                      const float* __restrict__ bx, const float* __restrict__ bbc,
                      const float* __restrict__ bd,
                      uint_t* __restrict__ AU, ushort_t* __restrict__ CYb,
                      float2* __restrict__ AHc)
{
    // GEMM phase: xs 64x72 bf16 (9216 B) + ws 4x64x72 bf16 (36864 B) = 46080 B
    // overlay phase: aus [64][65] float2 (33280) + comb [4][64] float2 (2048)
    //                + cs [64][72] bf16 (9216) = 44544 B
    __shared__ alignas(16) char smem[46080];
    ushort_t (*xs)[72]     = (ushort_t(*)[72])smem;
    ushort_t (*ws)[64][72] = (ushort_t(*)[64][72])(smem + 9216);
    float2   (*aus)[65]    = (float2(*)[65])smem;
    float2   (*comb)[64]   = (float2(*)[64])(smem + 33280);
    ushort_t (*cs)[72]     = (ushort_t(*)[72])(smem + 35328);

    const int tid  = threadIdx.x;
    const int wave = tid >> 6;
    const int lane = tid & 63;
    const int lm   = lane & 15;       // 16-dim index (row for A, n for B/D)
    const int lq   = lane >> 4;       // k-quad / row-quad
    const int row0 = blockIdx.x * 64;
    const int n0   = blockIdx.y * 64;

    // staging assignment: thread t -> row/n = t>>2, k-quad16 = (t&3)*16
    const int sr = tid >> 2;
    const int sk = (tid & 3) << 4;

    f32x4 acc[4][4];                  // [rowtile][mat]
    #pragma unroll
    for (int rt = 0; rt < 4; ++rt)
        #pragma unroll
        for (int m = 0; m < 4; ++m)
            acc[rt][m] = (f32x4){0.f, 0.f, 0.f, 0.f};

    const ushort_t* xsrc  = xb + (size_t)(row0 + sr) * CIN + sk;
    const ushort_t* wsrc0 = Wt + (size_t)(n0 + sr) * CIN + sk;   // mat stride = NST*CIN

    for (int k0 = 0; k0 < CIN; k0 += 64) {
        uint4 xv0 = *(const uint4*)(xsrc + k0);
        uint4 xv1 = *(const uint4*)(xsrc + k0 + 8);
        uint4 wv[4][2];
        #pragma unroll
        for (int m = 0; m < 4; ++m) {
            const ushort_t* p = wsrc0 + (size_t)m * NST * CIN + k0;
            wv[m][0] = *(const uint4*)(p);
            wv[m][1] = *(const uint4*)(p + 8);
        }
        *(uint4*)&xs[sr][sk]     = xv0;
        *(uint4*)&xs[sr][sk + 8] = xv1;
        #pragma unroll
        for (int m = 0; m < 4; ++m) {
            *(uint4*)&ws[m][sr][sk]     = wv[m][0];
            *(uint4*)&ws[m][sr][sk + 8] = wv[m][1];
        }
        __syncthreads();

        #pragma unroll
        for (int ks = 0; ks < 2; ++ks) {
            const int kk = ks * 32 + lq * 8;
            bf16x8 af[4], bf[4];
            #pragma unroll
            for (int rt = 0; rt < 4; ++rt)
                af[rt] = *(const bf16x8*)&xs[rt * 16 + lm][kk];
            #pragma unroll
            for (int m = 0; m < 4; ++m)
                bf[m] = *(const bf16x8*)&ws[m][wave * 16 + lm][kk];
            #pragma unroll
            for (int rt = 0; rt < 4; ++rt)
                #pragma unroll
                for (int m = 0; m < 4; ++m)
                    acc[rt][m] = __builtin_amdgcn_mfma_f32_16x16x32_bf16(
                        af[rt], bf[m], acc[rt][m], 0, 0, 0);
        }
        __syncthreads();   // fences last GEMM-phase LDS reads before overlay
    }

    // epilogue: in-lane, n fixed per lane. AU written directly (64 B-contiguous
    // per quarter-wave after fp16 packing); C staged to LDS for coalesced write.
    const int nl = wave * 16 + lm;    // local n within tile
    const int ng = n0 + nl;
    const float bxv = bx [ng];
    const float bbv = bbc[ng];
    const float bcv = bbc[NST + ng];
    const float bdv = bd [ng];
    #pragma unroll
    for (int rt = 0; rt < 4; ++rt) {
        #pragma unroll
        for (int r = 0; r < 4; ++r) {
            const int t   = rt * 16 + lq * 4 + r;    // 0..63 within tile
            const int row = row0 + t;
            float xp = acc[rt][0][r] + bxv;
            float bm = acc[rt][1][r] + bbv;
            float cc = acc[rt][2][r] + bcv;
            float dd = acc[rt][3][r] + bdv;
            dd = fminf(dd, 60.0f);
            float e  = __expf(dd);
            float A  = 1.0f / (1.0f + e);        // exp(-softplus(d))
            float u  = (e * A) * bm * xp;        // (1-A)*Bm*x_proj
            const size_t idx = (size_t)row * NST + ng;
            __half2 hv = __floats2half2_rn(A, u);
            __builtin_nontemporal_store(__builtin_bit_cast(uint_t, hv), &AU[idx]);
            aus[t][nl] = make_float2(A, u);
            cs[t][nl]  = f2bf(cc);
        }
    }
    __syncthreads();

    // coalesced C write: thread -> row = tid>>2, 16-n segment = (tid&3)*16
    {
        const int r  = tid >> 2;
        const int ns = (tid & 3) << 4;
        uint4 c0 = *(const uint4*)&cs[r][ns];
        uint4 c1 = *(const uint4*)&cs[r][ns + 8];
        ushort_t* dst = CYb + (size_t)(row0 + r) * NST + n0 + ns;
        *(uint4*)dst       = c0;
        *(uint4*)(dst + 8) = c1;
    }

    // chunk-local scan: 4 segments x 16 t each, one n-column per thread (fp32)
    {
        const int n  = tid & 63;
        const int sg = tid >> 6;                 // 0..3
        float ap = 1.0f, h = 0.0f;
        #pragma unroll
        for (int i = 0; i < 16; ++i) {
            float2 au = aus[sg * 16 + i][n];
            ap *= au.x;
            h  = fmaf(au.x, h, au.y);
        }
        comb[sg][n] = make_float2(ap, h);
    }
    __syncthreads();

    // combine segment pairs -> per-chunk (Aprod, Hend), interleaved float2.
    // global chunk id for this tile: 2*blockIdx.x + ch  (== b*NC + c)
    if (tid < 128) {
        const int n  = tid & 63;
        const int ch = tid >> 6;                 // 0..1
        float2 c0 = comb[ch * 2 + 0][n];
        float2 c1 = comb[ch * 2 + 1][n];
        const size_t ci = (size_t)(blockIdx.x * 2 + ch) * NST + (n0 + n);
        AHc[ci] = make_float2(c0.x * c1.x, fmaf(c1.x, c0.y, c1.y));
    }
}

// ---------------------------------------------------------------------------
// scan_carry: one WAVE per (b,n) column. Bulk-load all 128 chunk summaries,
// Kogge-Stone inclusive scan across 64 lanes (2 segments), coalesced Carry
// writes in [bn][c] layout. Replaces a 128-step serial global-memory chain.
// ---------------------------------------------------------------------------
__global__ __launch_bounds__(256)
void scan_carry_kernel(const float2* __restrict__ AHc, float* __restrict__ Carry2)
{
    const int wid  = (blockIdx.x * 256 + threadIdx.x) >> 6;  // 0..2047
    const int lane = threadIdx.x & 63;
    const int b = wid >> 9;         // 0..3
    const int n = wid & (NST - 1);

    // segment 0: chunks lane
    float2 v0 = AHc[(size_t)(b * NC + lane) * NST + n];
    float a = v0.x, h = v0.y;
    #pragma unroll
    for (int d = 1; d < 64; d <<= 1) {
        float ao = __shfl_up(a, d, 64);
        float ho = __shfl_up(h, d, 64);
        if (lane >= d) { h = fmaf(a, ho, h); a *= ao; }
    }
    float c0 = __shfl_up(h, 1, 64);
    if (lane == 0) c0 = 0.0f;
    const float Ht = __shfl(h, 63, 64);          // segment-0 total h

    // segment 1: chunks 64+lane
    float2 v1 = AHc[(size_t)(b * NC + 64 + lane) * NST + n];
    float a1 = v1.x, h1 = v1.y;
    #pragma unroll
    for (int d = 1; d < 64; d <<= 1) {
        float ao = __shfl_up(a1, d, 64);
        float ho = __shfl_up(h1, d, 64);
        if (lane >= d) { h1 = fmaf(a1, ho, h1); a1 *= ao; }
    }
    float pa = __shfl_up(a1, 1, 64);
    float ph = __shfl_up(h1, 1, 64);
    if (lane == 0) { pa = 1.0f; ph = 0.0f; }
    float c1 = fmaf(pa, Ht, ph);

    float* cp = Carry2 + (size_t)(b * NST + n) * NC;
    cp[lane]      = c0;      // 256 B contiguous per wave
    cp[64 + lane] = c1;
}

// ---------------------------------------------------------------------------
// scan_final: apply carries, produce y = C*h in-place (bf16 CYb).
// AU is packed fp16 (4 B/elem) — read traffic halved vs fp32 pairs.
// ---------------------------------------------------------------------------
__global__ __launch_bounds__(256)
void scan_final_kernel(const uint_t* __restrict__ AU, ushort_t* __restrict__ CYb,
                       const float* __restrict__ Carry2)
{
    const int gid = blockIdx.x * 256 + threadIdx.x;   // 0 .. BB*NC*NST-1
    const int n   = gid & (NST - 1);
    const int bc  = gid >> 9;                         // global chunk 0..511
    const int b   = bc >> 7;
    const int c   = bc & (NC - 1);
    const size_t base = (size_t)bc * LC * NST + n;
    float h = Carry2[((size_t)b * NST + n) * NC + c];
    #pragma unroll 8
    for (int t = 0; t < LC; ++t) {
        size_t idx = base + (size_t)t * NST;
        uint_t raw = __builtin_nontemporal_load(&AU[idx]);
        float2 au  = __half22float2(__builtin_bit_cast(__half2, raw));
        float cc   = bf2f(CYb[idx]);
        h = fmaf(au.x, h, au.y);
        CYb[idx] = f2bf(cc * h);     // y overwrites C (same slot, same thread)
    }
}

// ---------------------------------------------------------------------------
// out_mfma: out = y @ Wy + by via 16x16x32 bf16 MFMA. Tile 64 rows x 64 cols.
// ---------------------------------------------------------------------------
__global__ __launch_bounds__(256, 4)
void out_mfma_kernel(const ushort_t* __restrict__ yb, const ushort_t* __restrict__ Wyt,
                     const float* __restrict__ by, float* __restrict__ out)
{
    __shared__ alignas(16) ushort_t ys [64][72];
    __shared__ alignas(16) ushort_t wys[64][72];

    const int tid  = threadIdx.x;
    const int wave = tid >> 6;
    const int lane = tid & 63;
    const int lm   = lane & 15;
    const int lq   = lane >> 4;
    const int row0 = blockIdx.x * 64;
    const int n0   = blockIdx.y * 64;

    const int sr = tid >> 2;
    const int sk = (tid & 3) << 4;

    f32x4 acc[4];
    #pragma unroll
    for (int rt = 0; rt < 4; ++rt) acc[rt] = (f32x4){0.f, 0.f, 0.f, 0.f};

    const ushort_t* ysrc = yb  + (size_t)(row0 + sr) * NST + sk;
    const ushort_t* wsrc = Wyt + (size_t)(n0  + sr) * NST + sk;

    for (int k0 = 0; k0 < NST; k0 += 64) {
        uint4 yv0 = *(const uint4*)(ysrc + k0);
        uint4 yv1 = *(const uint4*)(ysrc + k0 + 8);
        uint4 wv0 = *(const uint4*)(wsrc + k0);
        uint4 wv1 = *(const uint4*)(wsrc + k0 + 8);
        *(uint4*)&ys [sr][sk]     = yv0;
        *(uint4*)&ys [sr][sk + 8] = yv1;
        *(uint4*)&wys[sr][sk]     = wv0;
        *(uint4*)&wys[sr][sk + 8] = wv1;
        __syncthreads();

        #pragma unroll
        for (int ks = 0; ks < 2; ++ks) {
            const int kk = ks * 32 + lq * 8;
            bf16x8 bfr = *(const bf16x8*)&wys[wave * 16 + lm][kk];
            #pragma unroll
            for (int rt = 0; rt < 4; ++rt) {
                bf16x8 af = *(const bf16x8*)&ys[rt * 16 + lm][kk];
                acc[rt] = __builtin_amdgcn_mfma_f32_16x16x32_bf16(
                    af, bfr, acc[rt], 0, 0, 0);
            }
        }
        __syncthreads();
    }

    const int ng = n0 + wave * 16 + lm;
    const float bv = by[ng];
    #pragma unroll
    for (int rt = 0; rt < 4; ++rt)
        #pragma unroll
        for (int r = 0; r < 4; ++r) {
            const int row = row0 + rt * 16 + lq * 4 + r;
            out[(size_t)row * COUT + ng] = acc[rt][r] + bv;
        }
}

// ---------------------------------------------------------------------------
// Workspace layout (bytes, all 16B aligned):
//   AU     fp16x2 ROWS*NST   33,554,432  (packed A,u)
//   CYb    bf16   ROWS*NST   16,777,216  (C from proj; y in-place after scan)
//   xb     bf16   ROWS*CIN    8,388,608
//   Wt     bf16   4*NST*CIN   1,048,576
//   Wyt    bf16   COUT*NST      262,144
//   AHc    float2 BB*NC*NST   2,097,152  (chunk Aprod,Hend interleaved)
//   Carry2 fp32   BB*NST*NC   1,048,576  ([bn][c] layout)
// total 63,176,704 B
// ---------------------------------------------------------------------------
extern "C" void kernel_launch(void* const* d_in, const int* in_sizes, int n_in,
                              void* d_out, int out_size, void* d_ws, size_t ws_size,
                              hipStream_t stream)
{
    const float* x   = (const float*)d_in[0];
    const float* Wx  = (const float*)d_in[1];
    const float* bx  = (const float*)d_in[2];
    const float* Wbc = (const float*)d_in[3];
    const float* bbc = (const float*)d_in[4];
    const float* Wd  = (const float*)d_in[5];
    const float* bd  = (const float*)d_in[6];
    const float* Wy  = (const float*)d_in[7];
    const float* by  = (const float*)d_in[8];
    float* out = (float*)d_out;

    char* p = (char*)d_ws;
    uint_t*   AU     = (uint_t*)p;        p += (size_t)ROWS * NST * 4;
    ushort_t* CYb    = (ushort_t*)p;      p += (size_t)ROWS * NST * 2;
    ushort_t* xb     = (ushort_t*)p;      p += (size_t)ROWS * CIN * 2;
    ushort_t* Wt     = (ushort_t*)p;      p += (size_t)4 * NST * CIN * 2;
    ushort_t* Wyt    = (ushort_t*)p;      p += (size_t)COUT * NST * 2;
    float2*   AHc    = (float2*)p;        p += (size_t)BB * NC * NST * 8;
    float*    Carry2 = (float*)p;         p += (size_t)BB * NST * NC * 4;

    prep_kernel<<<WBLOCKS + XBLOCKS, 256, 0, stream>>>(
        Wx, Wbc, Wd, Wy, x, Wt, Wyt, xb);

    proj_mfma_kernel<<<dim3(ROWS / 64, NST / 64), 256, 0, stream>>>(
        xb, Wt, bx, bbc, bd, AU, CYb, AHc);

    scan_carry_kernel<<<(BB * NST) / 4, 256, 0, stream>>>(AHc, Carry2);

    scan_final_kernel<<<(BB * NC * NST) / 256, 256, 0, stream>>>(
        AU, CYb, Carry2);

    out_mfma_kernel<<<dim3(ROWS / 64, COUT / 64), 256, 0, stream>>>(
        CYb, Wyt, by, out);
}